// Round 1
// baseline (510.421 us; speedup 1.0000x reference)
//
#include <hip/hip_runtime.h>
#include <math.h>

#define NNODE 65536
#define NEDGE 1048576
#define NGRAPH 128
#define NPG 512

// ---------------- init / CSR build ----------------

__global__ __launch_bounds__(256) void k_init(float* maskf, float* gate, int* alive) {
    int i = blockIdx.x * 256 + threadIdx.x;
    maskf[i] = 1.f; gate[i] = 1.f; alive[i] = i;
}

__global__ __launch_bounds__(256) void k_count(const int* __restrict__ dst, int* __restrict__ cnt) {
    int e = blockIdx.x * 256 + threadIdx.x;
    atomicAdd(&cnt[dst[e]], 1);
}

__global__ __launch_bounds__(256) void k_scan1(const int* __restrict__ cnt, int* __restrict__ rp,
                                               int* __restrict__ bsum) {
    __shared__ int sh[256];
    int t = threadIdx.x, i = blockIdx.x * 256 + t;
    int v = cnt[i], incl = v;
    for (int off = 1; off < 256; off <<= 1) {
        sh[t] = incl; __syncthreads();
        if (t >= off) incl += sh[t - off];
        __syncthreads();
    }
    rp[i] = incl - v;
    if (t == 255) bsum[blockIdx.x] = incl;
}

__global__ __launch_bounds__(256) void k_scan2(const int* __restrict__ bsum, int* __restrict__ boff,
                                               int* __restrict__ rp) {
    __shared__ int sh[256];
    int t = threadIdx.x;
    int v = bsum[t], incl = v;
    for (int off = 1; off < 256; off <<= 1) {
        sh[t] = incl; __syncthreads();
        if (t >= off) incl += sh[t - off];
        __syncthreads();
    }
    boff[t] = incl - v;
    if (t == 255) rp[NNODE] = incl;
}

__global__ __launch_bounds__(256) void k_scan3(int* __restrict__ rp, const int* __restrict__ boff) {
    int i = blockIdx.x * 256 + threadIdx.x;
    rp[i] += boff[blockIdx.x];
}

__global__ __launch_bounds__(256) void k_fill(const int* __restrict__ src, const int* __restrict__ dst,
                                              const int* __restrict__ rp, int* __restrict__ cur,
                                              int* __restrict__ csr) {
    int e = blockIdx.x * 256 + threadIdx.x;
    int d = dst[e];
    int pos = rp[d] + atomicAdd(&cur[d], 1);
    csr[pos] = src[e];
}

// ---------------- per-layer kernels ----------------

// dinv[d] = mask[d] ? rsqrt(1 + sum_in mask[src]) : 0  (folds mask into dinv)
__global__ __launch_bounds__(256) void k_deg(const float* __restrict__ maskf, const int* __restrict__ rp,
                                             const int* __restrict__ csr, float* __restrict__ dinv) {
    int i = blockIdx.x * 256 + threadIdx.x;
    float m = maskf[i];
    float dv = 0.f;
    if (m > 0.f) {
        int jb = rp[i], je = rp[i + 1];
        float s = 1.f;
        for (int j = jb; j < je; ++j) s += maskf[csr[j]];
        dv = rsqrtf(s);
    }
    dinv[i] = dv;
}

// h[alive rows] = (x * gate) @ W ; 64-row x 64-col tile per block, W k-halved in LDS.
#define ACC4(A, X, W0, W1) \
    A.x = fmaf(X.x, W0.x, A.x); A.x = fmaf(X.y, W1.x, A.x); \
    A.y = fmaf(X.x, W0.y, A.y); A.y = fmaf(X.y, W1.y, A.y); \
    A.z = fmaf(X.x, W0.z, A.z); A.z = fmaf(X.y, W1.z, A.z); \
    A.w = fmaf(X.x, W0.w, A.w); A.w = fmaf(X.y, W1.w, A.w);

__global__ __launch_bounds__(256) void k_gemm(const float* __restrict__ x, const float* __restrict__ W,
                                              const float* __restrict__ gate, const int* __restrict__ alive,
                                              float* __restrict__ h) {
    __shared__ float xs[64 * 128];  // 32 KB
    __shared__ float ws[64 * 64];   // 16 KB (one k-half of the 64-col slab)
    int t = threadIdx.x;
    int rowbase = blockIdx.x * 64;
    int colbase = blockIdx.y * 64;

    // stage x (gated): 64 rows x 128 cols = 2048 float4s
    for (int p = 0; p < 8; ++p) {
        int i = t + p * 256;
        int r = i >> 5, q = i & 31;
        int nd = alive[rowbase + r];
        float g = gate[nd];
        float4 v = *(const float4*)(x + (size_t)nd * 128 + q * 4);
        v.x *= g; v.y *= g; v.z *= g; v.w *= g;
        *(float4*)(xs + r * 128 + q * 4) = v;
    }

    int c4 = (t & 15) * 4;
    int rb = (t >> 4) * 4;
    float4 a0 = {0, 0, 0, 0}, a1 = a0, a2 = a0, a3 = a0;

    for (int kh = 0; kh < 2; ++kh) {
        if (kh) __syncthreads();
        // stage W half: 64 k x 64 cols = 1024 float4s
        for (int p = 0; p < 4; ++p) {
            int i = t + p * 256;
            int kk = i >> 4, q = i & 15;
            *(float4*)(ws + kk * 64 + q * 4) =
                *(const float4*)(W + (size_t)(kh * 64 + kk) * 128 + colbase + q * 4);
        }
        __syncthreads();
        int kb = kh * 64;
        for (int k = 0; k < 64; k += 2) {
            float4 w0 = *(const float4*)(ws + k * 64 + c4);
            float4 w1 = *(const float4*)(ws + (k + 1) * 64 + c4);
            float2 x0 = *(const float2*)(xs + (rb + 0) * 128 + kb + k);
            float2 x1 = *(const float2*)(xs + (rb + 1) * 128 + kb + k);
            float2 x2 = *(const float2*)(xs + (rb + 2) * 128 + kb + k);
            float2 x3 = *(const float2*)(xs + (rb + 3) * 128 + kb + k);
            ACC4(a0, x0, w0, w1); ACC4(a1, x1, w0, w1);
            ACC4(a2, x2, w0, w1); ACC4(a3, x3, w0, w1);
        }
    }

    int n0 = alive[rowbase + rb + 0];
    int n1 = alive[rowbase + rb + 1];
    int n2 = alive[rowbase + rb + 2];
    int n3 = alive[rowbase + rb + 3];
    *(float4*)(h + (size_t)n0 * 128 + colbase + c4) = a0;
    *(float4*)(h + (size_t)n1 * 128 + colbase + c4) = a1;
    *(float4*)(h + (size_t)n2 * 128 + colbase + c4) = a2;
    *(float4*)(h + (size_t)n3 * 128 + colbase + c4) = a3;
}

// out[d] = relu(dinv_d * (sum_in dinv_s*h[s] + dinv_d*h[d]) + b)  for alive d. Wave per node.
__global__ __launch_bounds__(256) void k_agg(const float* __restrict__ h, const float* __restrict__ dinv,
                                             const int* __restrict__ rp, const int* __restrict__ csr,
                                             const int* __restrict__ alive, const float* __restrict__ bias,
                                             float* __restrict__ out) {
    int lane = threadIdx.x & 63;
    int idx = blockIdx.x * 4 + (threadIdx.x >> 6);
    int d = __builtin_amdgcn_readfirstlane(alive[idx]);
    float dv_d = dinv[d];
    int jb = __builtin_amdgcn_readfirstlane(rp[d]);
    int je = __builtin_amdgcn_readfirstlane(rp[d + 1]);
    float2 hd = *(const float2*)(h + (size_t)d * 128 + 2 * lane);
    float ax = dv_d * hd.x, ay = dv_d * hd.y;
    for (int j = jb; j < je; ++j) {
        int s = __builtin_amdgcn_readfirstlane(csr[j]);
        float dvs = dinv[s];
        if (dvs != 0.f) {
            float2 hv = *(const float2*)(h + (size_t)s * 128 + 2 * lane);
            ax = fmaf(dvs, hv.x, ax);
            ay = fmaf(dvs, hv.y, ay);
        }
    }
    float2 b2 = *(const float2*)(bias + 2 * lane);
    float2 o;
    o.x = fmaxf(fmaf(dv_d, ax, b2.x), 0.f);
    o.y = fmaxf(fmaf(dv_d, ay, b2.y), 0.f);
    *(float2*)(out + (size_t)d * 128 + 2 * lane) = o;
}

// score[d] = sigmoid((x[d]·p)/||p||), wave per alive node
__global__ __launch_bounds__(256) void k_score(const float* __restrict__ xb, const float* __restrict__ p,
                                               const int* __restrict__ alive, float* __restrict__ score) {
    int lane = threadIdx.x & 63;
    int idx = blockIdx.x * 4 + (threadIdx.x >> 6);
    int d = __builtin_amdgcn_readfirstlane(alive[idx]);
    float pa = p[lane], pb = p[64 + lane];
    float va = xb[(size_t)d * 128 + lane], vb = xb[(size_t)d * 128 + 64 + lane];
    float z = va * pa + vb * pb;
    float q = pa * pa + pb * pb;
    for (int m = 32; m > 0; m >>= 1) {
        z += __shfl_xor(z, m);
        q += __shfl_xor(q, m);
    }
    if (lane == 0) score[d] = 1.f / (1.f + expf(-z * rsqrtf(q)));
}

// per-graph: descending bitonic sort of 512 masked scores -> threshold = K-th; update mask/gate/alive
__global__ __launch_bounds__(512) void k_topk(const float* __restrict__ score, float* __restrict__ maskf,
                                              float* __restrict__ gate, int* __restrict__ alive, int K) {
    __shared__ float s[512];
    __shared__ int scnt;
    int t = threadIdx.x, g = blockIdx.x;
    int d = g * 512 + t;
    float m = maskf[d];
    float sc = score[d];
    if (t == 0) scnt = 0;
    s[t] = (m > 0.f) ? sc : -__builtin_inff();
    __syncthreads();
    for (int k2 = 2; k2 <= 512; k2 <<= 1)
        for (int j = k2 >> 1; j > 0; j >>= 1) {
            int ixj = t ^ j;
            if (ixj > t) {
                float a = s[t], bv = s[ixj];
                bool sw = ((t & k2) == 0) ? (a < bv) : (a > bv);  // descending overall
                if (sw) { s[t] = bv; s[ixj] = a; }
            }
            __syncthreads();
        }
    float thr = s[K - 1];
    int nm = (m > 0.f && sc >= thr) ? 1 : 0;
    maskf[d] = (float)nm;
    gate[d] = nm ? sc : 0.f;
    if (nm) {
        int pos = atomicAdd(&scnt, 1);
        if (pos < K) alive[g * K + pos] = d;
    }
}

// readout: hg[g] += [max_f over alive of x*gate ; mean_f]  (values >=0, relu is identity)
__global__ __launch_bounds__(512) void k_readout(const float* __restrict__ xb, const float* __restrict__ gate,
                                                 const int* __restrict__ alive, float* __restrict__ hg, int K) {
    __shared__ int ad[256];
    __shared__ float ag[256];
    __shared__ float red[1024];
    int t = threadIdx.x, g = blockIdx.x;
    if (t < K) {
        int a = alive[g * K + t];
        ad[t] = a;
        ag[t] = gate[a];
    }
    __syncthreads();
    int f = t & 127, c = t >> 7;  // c in 0..3
    float mx = 0.f, sm = 0.f;
    for (int j = c; j < K; j += 4) {
        float v = xb[(size_t)ad[j] * 128 + f] * ag[j];
        mx = fmaxf(mx, v);
        sm += v;
    }
    red[t] = mx; red[512 + t] = sm;
    __syncthreads();
    if (c == 0) {
        for (int cc = 1; cc < 4; ++cc) {
            mx = fmaxf(mx, red[cc * 128 + f]);
            sm += red[512 + cc * 128 + f];
        }
        hg[g * 256 + f] += mx;
        hg[g * 256 + 128 + f] += sm / (float)K;
    }
}

// fused head: embed -> concat -> 2x relu-linear -> final dot. One block per graph.
__global__ __launch_bounds__(256) void k_mlp(const float* __restrict__ inp_c, const float* __restrict__ hg,
                                             const float* __restrict__ We, const float* __restrict__ Wa,
                                             const float* __restrict__ ba, const float* __restrict__ Wb,
                                             const float* __restrict__ bb, const float* __restrict__ Wc,
                                             float* __restrict__ out) {
    __shared__ float fus[320];
    __shared__ float h1[256];
    __shared__ float h2[128];
    int t = threadIdx.x, g = blockIdx.x;
    if (t < 64) {
        float a = 0.f;
        for (int j = 0; j < 64; ++j) a = fmaf(inp_c[g * 64 + j], We[j * 64 + t], a);
        fus[t] = fmaxf(a, 0.f);
    }
    fus[64 + t] = hg[g * 256 + t];
    __syncthreads();
    {
        float a = ba[t];
        for (int j = 0; j < 320; ++j) a = fmaf(fus[j], Wa[j * 256 + t], a);
        h1[t] = fmaxf(a, 0.f);
    }
    __syncthreads();
    if (t < 128) {
        float a = bb[t];
        for (int j = 0; j < 256; ++j) a = fmaf(h1[j], Wb[j * 128 + t], a);
        h2[t] = fmaxf(a, 0.f);
    }
    __syncthreads();
    if (t == 0) {
        float a = 0.f;
        for (int j = 0; j < 128; ++j) a = fmaf(h2[j], Wc[j], a);
        out[g] = a;
    }
}

// ---------------- launch ----------------

extern "C" void kernel_launch(void* const* d_in, const int* in_sizes, int n_in,
                              void* d_out, int out_size, void* d_ws, size_t ws_size,
                              hipStream_t stream) {
    (void)in_sizes; (void)n_in; (void)out_size; (void)ws_size;
    const float* x_in  = (const float*)d_in[0];
    const float* inp_c = (const float*)d_in[1];
    const int*   ei    = (const int*)d_in[2];
    const int* srcE = ei;
    const int* dstE = ei + NEDGE;
    const float* Wl[3] = {(const float*)d_in[4], (const float*)d_in[6], (const float*)d_in[8]};
    const float* bl[3] = {(const float*)d_in[5], (const float*)d_in[7], (const float*)d_in[9]};
    const float* Pl[3] = {(const float*)d_in[10], (const float*)d_in[11], (const float*)d_in[12]};
    const float* We = (const float*)d_in[13];
    const float* Wa = (const float*)d_in[14];
    const float* ba = (const float*)d_in[15];
    const float* Wb = (const float*)d_in[16];
    const float* bb = (const float*)d_in[17];
    const float* Wc = (const float*)d_in[18];
    float* out = (float*)d_out;

    char* w = (char*)d_ws;
    size_t off = 0;
    auto alloc = [&](size_t bytes) -> void* {
        void* p = w + off;
        off = (off + bytes + 255) & ~(size_t)255;
        return p;
    };
    int*   rp    = (int*)alloc((NNODE + 1) * 4);
    int*   cnt   = (int*)alloc(NNODE * 4);
    int*   csr   = (int*)alloc((NEDGE + 256) * 4);
    int*   bsum  = (int*)alloc(256 * 4);
    int*   boff  = (int*)alloc(256 * 4);
    float* dinv  = (float*)alloc(NNODE * 4);
    float* maskf = (float*)alloc(NNODE * 4);
    float* gate  = (float*)alloc(NNODE * 4);
    float* score = (float*)alloc(NNODE * 4);
    int*   alive = (int*)alloc(NNODE * 4);
    float* hbuf  = (float*)alloc((size_t)NNODE * 128 * 4);
    float* xbuf  = (float*)alloc((size_t)NNODE * 128 * 4);
    float* hg    = (float*)alloc(NGRAPH * 256 * 4);

    hipMemsetAsync(cnt, 0, NNODE * 4, stream);
    hipMemsetAsync(hg, 0, NGRAPH * 256 * 4, stream);
    k_init<<<NNODE / 256, 256, 0, stream>>>(maskf, gate, alive);
    k_count<<<NEDGE / 256, 256, 0, stream>>>(dstE, cnt);
    k_scan1<<<256, 256, 0, stream>>>(cnt, rp, bsum);
    k_scan2<<<1, 256, 0, stream>>>(bsum, boff, rp);
    k_scan3<<<256, 256, 0, stream>>>(rp, boff);
    hipMemsetAsync(cnt, 0, NNODE * 4, stream);
    k_fill<<<NEDGE / 256, 256, 0, stream>>>(srcE, dstE, rp, cnt, csr);

    const int rows_in[3] = {65536, 32768, 16384};
    const int Ks[3] = {256, 128, 64};
    for (int l = 0; l < 3; ++l) {
        const float* xin = (l == 0) ? x_in : xbuf;
        k_deg<<<NNODE / 256, 256, 0, stream>>>(maskf, rp, csr, dinv);
        k_gemm<<<dim3(rows_in[l] / 64, 2), 256, 0, stream>>>(xin, Wl[l], gate, alive, hbuf);
        k_agg<<<rows_in[l] / 4, 256, 0, stream>>>(hbuf, dinv, rp, csr, alive, bl[l], xbuf);
        k_score<<<rows_in[l] / 4, 256, 0, stream>>>(xbuf, Pl[l], alive, score);
        k_topk<<<NGRAPH, 512, 0, stream>>>(score, maskf, gate, alive, Ks[l]);
        k_readout<<<NGRAPH, 512, 0, stream>>>(xbuf, gate, alive, hg, Ks[l]);
    }
    k_mlp<<<NGRAPH, 256, 0, stream>>>(inp_c, hg, We, Wa, ba, Wb, bb, Wc, out);
}

// Round 2
// 376.781 us; speedup vs baseline: 1.3547x; 1.3547x over previous
//
#include <hip/hip_runtime.h>
#include <math.h>

#define NNODE 65536
#define NEDGE 1048576
#define NGRAPH 128
#define NPG 512
#define EPG 8192

// ---------------- CSR build: one block per graph (LDS count/scan/fill) + node-state init --------

__global__ __launch_bounds__(512) void k_csr(const int* __restrict__ srcE, const int* __restrict__ dstE,
                                             int* __restrict__ rp, int* __restrict__ csr,
                                             float* __restrict__ maskf, float* __restrict__ gate,
                                             int* __restrict__ alive) {
    __shared__ int cnt[512];
    __shared__ int tmp[512];
    int g = blockIdx.x, t = threadIdx.x;
    int nd = g * NPG + t;
    cnt[t] = 0;
    maskf[nd] = 1.f;
    gate[nd] = 1.f;
    alive[nd] = nd;
    __syncthreads();
    int ebase = g * EPG;
    int dl[16];
    for (int i = 0; i < 16; ++i) {
        int e = ebase + t + i * 512;
        int d = dstE[e] - g * NPG;
        dl[i] = d;
        atomicAdd(&cnt[d], 1);
    }
    __syncthreads();
    int v = cnt[t], incl = v;
    for (int off = 1; off < 512; off <<= 1) {
        tmp[t] = incl; __syncthreads();
        if (t >= off) incl += tmp[t - off];
        __syncthreads();
    }
    int excl = incl - v;
    rp[nd] = ebase + excl;
    if (g == NGRAPH - 1 && t == 511) rp[NNODE] = NEDGE;
    __syncthreads();
    cnt[t] = excl;
    __syncthreads();
    for (int i = 0; i < 16; ++i) {
        int e = ebase + t + i * 512;
        int pos = atomicAdd(&cnt[dl[i]], 1);
        csr[ebase + pos] = srcE[e];
    }
}

// ---------------- dinv[d] = mask[d] ? rsqrt(1 + sum_in mask[src]) : 0 ----------------

__global__ __launch_bounds__(256) void k_deg(const float* __restrict__ maskf, const int* __restrict__ rp,
                                             const int* __restrict__ csr, float* __restrict__ dinv) {
    int i = blockIdx.x * 256 + threadIdx.x;
    float m = maskf[i];
    float dv = 0.f;
    if (m > 0.f) {
        int jb = rp[i], je = rp[i + 1];
        float s0 = 1.f, s1 = 0.f, s2 = 0.f, s3 = 0.f;
        int j = jb;
        for (; j + 4 <= je; j += 4) {
            s0 += maskf[csr[j]];
            s1 += maskf[csr[j + 1]];
            s2 += maskf[csr[j + 2]];
            s3 += maskf[csr[j + 3]];
        }
        for (; j < je; ++j) s0 += maskf[csr[j]];
        dv = rsqrtf(s0 + s1 + s2 + s3);
    }
    dinv[i] = dv;
}

// ---------------- h[alive rows] = (x * gate) @ W ----------------

#define ACC4(A, X, W0, W1) \
    A.x = fmaf(X.x, W0.x, A.x); A.x = fmaf(X.y, W1.x, A.x); \
    A.y = fmaf(X.x, W0.y, A.y); A.y = fmaf(X.y, W1.y, A.y); \
    A.z = fmaf(X.x, W0.z, A.z); A.z = fmaf(X.y, W1.z, A.z); \
    A.w = fmaf(X.x, W0.w, A.w); A.w = fmaf(X.y, W1.w, A.w);

__global__ __launch_bounds__(256) void k_gemm(const float* __restrict__ x, const float* __restrict__ W,
                                              const float* __restrict__ gate, const int* __restrict__ alive,
                                              float* __restrict__ h) {
    __shared__ float xs[64 * 128];
    __shared__ float ws[64 * 64];
    int t = threadIdx.x;
    int rowbase = blockIdx.x * 64;
    int colbase = blockIdx.y * 64;

    for (int p = 0; p < 8; ++p) {
        int i = t + p * 256;
        int r = i >> 5, q = i & 31;
        int nd = alive[rowbase + r];
        float g = gate[nd];
        float4 v = *(const float4*)(x + (size_t)nd * 128 + q * 4);
        v.x *= g; v.y *= g; v.z *= g; v.w *= g;
        *(float4*)(xs + r * 128 + q * 4) = v;
    }

    int c4 = (t & 15) * 4;
    int rb = (t >> 4) * 4;
    float4 a0 = {0, 0, 0, 0}, a1 = a0, a2 = a0, a3 = a0;

    for (int kh = 0; kh < 2; ++kh) {
        if (kh) __syncthreads();
        for (int p = 0; p < 4; ++p) {
            int i = t + p * 256;
            int kk = i >> 4, q = i & 15;
            *(float4*)(ws + kk * 64 + q * 4) =
                *(const float4*)(W + (size_t)(kh * 64 + kk) * 128 + colbase + q * 4);
        }
        __syncthreads();
        int kb = kh * 64;
        for (int k = 0; k < 64; k += 2) {
            float4 w0 = *(const float4*)(ws + k * 64 + c4);
            float4 w1 = *(const float4*)(ws + (k + 1) * 64 + c4);
            float2 x0 = *(const float2*)(xs + (rb + 0) * 128 + kb + k);
            float2 x1 = *(const float2*)(xs + (rb + 1) * 128 + kb + k);
            float2 x2 = *(const float2*)(xs + (rb + 2) * 128 + kb + k);
            float2 x3 = *(const float2*)(xs + (rb + 3) * 128 + kb + k);
            ACC4(a0, x0, w0, w1); ACC4(a1, x1, w0, w1);
            ACC4(a2, x2, w0, w1); ACC4(a3, x3, w0, w1);
        }
    }

    int n0 = alive[rowbase + rb + 0];
    int n1 = alive[rowbase + rb + 1];
    int n2 = alive[rowbase + rb + 2];
    int n3 = alive[rowbase + rb + 3];
    *(float4*)(h + (size_t)n0 * 128 + colbase + c4) = a0;
    *(float4*)(h + (size_t)n1 * 128 + colbase + c4) = a1;
    *(float4*)(h + (size_t)n2 * 128 + colbase + c4) = a2;
    *(float4*)(h + (size_t)n3 * 128 + colbase + c4) = a3;
}

// ---------------- agg + relu + fused score ----------------
// Wave per alive node. Lanes prefetch neighbor (idx,dinv) in parallel; unrolled h-gather.
// XCD swizzle: all blocks of a graph share blockIdx%8 so the graph's h-tile stays in one L2.

__global__ __launch_bounds__(256) void k_agg(const float* __restrict__ h, const float* __restrict__ dinv,
                                             const int* __restrict__ rp, const int* __restrict__ csr,
                                             const int* __restrict__ alive, const float* __restrict__ bias,
                                             const float* __restrict__ p, float* __restrict__ out,
                                             float* __restrict__ score, int P, int p2) {
    __shared__ int   sid[4][64];
    __shared__ float sdw[4][64];
    int w = threadIdx.x >> 6, lane = threadIdx.x & 63;
    int b = blockIdx.x;
    int xcd = b & 7, i = b >> 3;
    int chunk = (((i >> p2) * 8 + xcd) << p2) + (i & (P - 1));
    int idx = chunk * 4 + w;

    int d = __builtin_amdgcn_readfirstlane(alive[idx]);
    int jb = __builtin_amdgcn_readfirstlane(rp[d]);
    int je = __builtin_amdgcn_readfirstlane(rp[d + 1]);
    int deg = je - jb;

    int si = 0; float sv = 0.f;
    if (lane < deg) {
        si = csr[jb + lane];
        sv = dinv[si];
    }
    sid[w][lane] = si;
    sdw[w][lane] = sv;

    float dv_d = dinv[d];
    float2 hd = *(const float2*)(h + (size_t)d * 128 + 2 * lane);
    float a0x = dv_d * hd.x, a0y = dv_d * hd.y;
    float a1x = 0.f, a1y = 0.f, a2x = 0.f, a2y = 0.f, a3x = 0.f, a3y = 0.f;

    int dc = deg > 64 ? 64 : deg;
    int j = 0;
    for (; j + 4 <= dc; j += 4) {
        int s0 = sid[w][j + 0]; float v0 = sdw[w][j + 0];
        int s1 = sid[w][j + 1]; float v1 = sdw[w][j + 1];
        int s2 = sid[w][j + 2]; float v2 = sdw[w][j + 2];
        int s3 = sid[w][j + 3]; float v3 = sdw[w][j + 3];
        float2 h0 = *(const float2*)(h + (size_t)s0 * 128 + 2 * lane);
        float2 h1 = *(const float2*)(h + (size_t)s1 * 128 + 2 * lane);
        float2 h2 = *(const float2*)(h + (size_t)s2 * 128 + 2 * lane);
        float2 h3 = *(const float2*)(h + (size_t)s3 * 128 + 2 * lane);
        a0x = fmaf(v0, h0.x, a0x); a0y = fmaf(v0, h0.y, a0y);
        a1x = fmaf(v1, h1.x, a1x); a1y = fmaf(v1, h1.y, a1y);
        a2x = fmaf(v2, h2.x, a2x); a2y = fmaf(v2, h2.y, a2y);
        a3x = fmaf(v3, h3.x, a3x); a3y = fmaf(v3, h3.y, a3y);
    }
    for (; j < dc; ++j) {
        int s0 = sid[w][j]; float v0 = sdw[w][j];
        float2 h0 = *(const float2*)(h + (size_t)s0 * 128 + 2 * lane);
        a0x = fmaf(v0, h0.x, a0x); a0y = fmaf(v0, h0.y, a0y);
    }
    for (int jj = jb + 64; jj < je; ++jj) {  // overflow path (deg>64), practically never
        int s0 = csr[jj]; float v0 = dinv[s0];
        float2 h0 = *(const float2*)(h + (size_t)s0 * 128 + 2 * lane);
        a0x = fmaf(v0, h0.x, a0x); a0y = fmaf(v0, h0.y, a0y);
    }

    float sx = a0x + a1x + a2x + a3x;
    float sy = a0y + a1y + a2y + a3y;
    float2 b2 = *(const float2*)(bias + 2 * lane);
    float ox = fmaxf(fmaf(dv_d, sx, b2.x), 0.f);
    float oy = fmaxf(fmaf(dv_d, sy, b2.y), 0.f);
    float2 o; o.x = ox; o.y = oy;
    *(float2*)(out + (size_t)d * 128 + 2 * lane) = o;

    // fused score: sigmoid((out . p) / ||p||)
    float2 p2v = *(const float2*)(p + 2 * lane);
    float z = ox * p2v.x + oy * p2v.y;
    float qn = p2v.x * p2v.x + p2v.y * p2v.y;
    for (int m = 32; m > 0; m >>= 1) {
        z += __shfl_xor(z, m);
        qn += __shfl_xor(qn, m);
    }
    if (lane == 0) score[d] = 1.f / (1.f + expf(-z * rsqrtf(qn)));
}

// ---------------- fused top-k pool + readout ----------------

__global__ __launch_bounds__(512) void k_pool(const float* __restrict__ xb, const float* __restrict__ score,
                                              float* __restrict__ maskf, float* __restrict__ gate,
                                              int* __restrict__ alive, float* __restrict__ hg, int K) {
    __shared__ float s[512];
    __shared__ int ad[256];
    __shared__ float ag[256];
    __shared__ float red[1024];
    __shared__ int scnt;
    int t = threadIdx.x, g = blockIdx.x;
    int d = g * NPG + t;
    float m = maskf[d];
    float sc = score[d];
    if (t == 0) scnt = 0;
    s[t] = (m > 0.f) ? sc : -__builtin_inff();
    __syncthreads();
    for (int k2 = 2; k2 <= 512; k2 <<= 1)
        for (int j = k2 >> 1; j > 0; j >>= 1) {
            int ixj = t ^ j;
            if (ixj > t) {
                float a = s[t], bv = s[ixj];
                bool sw = ((t & k2) == 0) ? (a < bv) : (a > bv);
                if (sw) { s[t] = bv; s[ixj] = a; }
            }
            __syncthreads();
        }
    float thr = s[K - 1];
    int nm = (m > 0.f && sc >= thr) ? 1 : 0;
    maskf[d] = (float)nm;
    gate[d] = nm ? sc : 0.f;
    if (nm) {
        int pos = atomicAdd(&scnt, 1);
        if (pos < K) {
            alive[g * K + pos] = d;
            ad[pos] = d;
            ag[pos] = sc;
        }
    }
    __syncthreads();
    // readout on the NEW alive set (values >= 0 so outer relu is identity)
    int f = t & 127, c = t >> 7;
    float mx = 0.f, sm = 0.f;
    for (int j = c; j < K; j += 4) {
        float v = xb[(size_t)ad[j] * 128 + f] * ag[j];
        mx = fmaxf(mx, v);
        sm += v;
    }
    red[t] = mx; red[512 + t] = sm;
    __syncthreads();
    if (c == 0) {
        for (int cc = 1; cc < 4; ++cc) {
            mx = fmaxf(mx, red[cc * 128 + f]);
            sm += red[512 + cc * 128 + f];
        }
        hg[g * 256 + f] += mx;
        hg[g * 256 + 128 + f] += sm / (float)K;
    }
}

// ---------------- fused MLP head ----------------

__global__ __launch_bounds__(256) void k_mlp(const float* __restrict__ inp_c, const float* __restrict__ hg,
                                             const float* __restrict__ We, const float* __restrict__ Wa,
                                             const float* __restrict__ ba, const float* __restrict__ Wb,
                                             const float* __restrict__ bb, const float* __restrict__ Wc,
                                             float* __restrict__ out) {
    __shared__ float fus[320];
    __shared__ float h1[256];
    __shared__ float h2[128];
    int t = threadIdx.x, g = blockIdx.x;
    if (t < 64) {
        float a = 0.f;
        for (int j = 0; j < 64; ++j) a = fmaf(inp_c[g * 64 + j], We[j * 64 + t], a);
        fus[t] = fmaxf(a, 0.f);
    }
    fus[64 + t] = hg[g * 256 + t];
    __syncthreads();
    {
        float a = ba[t];
        for (int j = 0; j < 320; ++j) a = fmaf(fus[j], Wa[j * 256 + t], a);
        h1[t] = fmaxf(a, 0.f);
    }
    __syncthreads();
    if (t < 128) {
        float a = bb[t];
        for (int j = 0; j < 256; ++j) a = fmaf(h1[j], Wb[j * 128 + t], a);
        h2[t] = fmaxf(a, 0.f);
    }
    __syncthreads();
    if (t == 0) {
        float a = 0.f;
        for (int j = 0; j < 128; ++j) a = fmaf(h2[j], Wc[j], a);
        out[g] = a;
    }
}

// ---------------- launch ----------------

extern "C" void kernel_launch(void* const* d_in, const int* in_sizes, int n_in,
                              void* d_out, int out_size, void* d_ws, size_t ws_size,
                              hipStream_t stream) {
    (void)in_sizes; (void)n_in; (void)out_size; (void)ws_size;
    const float* x_in  = (const float*)d_in[0];
    const float* inp_c = (const float*)d_in[1];
    const int*   ei    = (const int*)d_in[2];
    const int* srcE = ei;
    const int* dstE = ei + NEDGE;
    const float* Wl[3] = {(const float*)d_in[4], (const float*)d_in[6], (const float*)d_in[8]};
    const float* bl[3] = {(const float*)d_in[5], (const float*)d_in[7], (const float*)d_in[9]};
    const float* Pl[3] = {(const float*)d_in[10], (const float*)d_in[11], (const float*)d_in[12]};
    const float* We = (const float*)d_in[13];
    const float* Wa = (const float*)d_in[14];
    const float* ba = (const float*)d_in[15];
    const float* Wb = (const float*)d_in[16];
    const float* bb = (const float*)d_in[17];
    const float* Wc = (const float*)d_in[18];
    float* out = (float*)d_out;

    char* w = (char*)d_ws;
    size_t off = 0;
    auto alloc = [&](size_t bytes) -> void* {
        void* p = w + off;
        off = (off + bytes + 255) & ~(size_t)255;
        return p;
    };
    int*   rp    = (int*)alloc((NNODE + 1) * 4);
    int*   csr   = (int*)alloc(NEDGE * 4);
    float* dinv  = (float*)alloc(NNODE * 4);
    float* maskf = (float*)alloc(NNODE * 4);
    float* gate  = (float*)alloc(NNODE * 4);
    float* score = (float*)alloc(NNODE * 4);
    int*   alive = (int*)alloc(NNODE * 4);
    float* hbuf  = (float*)alloc((size_t)NNODE * 128 * 4);
    float* xbuf  = (float*)alloc((size_t)NNODE * 128 * 4);
    float* hg    = (float*)alloc(NGRAPH * 256 * 4);

    hipMemsetAsync(hg, 0, NGRAPH * 256 * 4, stream);
    k_csr<<<NGRAPH, 512, 0, stream>>>(srcE, dstE, rp, csr, maskf, gate, alive);

    const int rows_in[3] = {65536, 32768, 16384};
    const int Ks[3] = {256, 128, 64};
    const int Pg[3] = {128, 64, 32};   // agg blocks per graph
    const int p2g[3] = {7, 6, 5};
    for (int l = 0; l < 3; ++l) {
        const float* xin = (l == 0) ? x_in : xbuf;
        k_deg<<<NNODE / 256, 256, 0, stream>>>(maskf, rp, csr, dinv);
        k_gemm<<<dim3(rows_in[l] / 64, 2), 256, 0, stream>>>(xin, Wl[l], gate, alive, hbuf);
        k_agg<<<rows_in[l] / 4, 256, 0, stream>>>(hbuf, dinv, rp, csr, alive, bl[l], Pl[l],
                                                  xbuf, score, Pg[l], p2g[l]);
        k_pool<<<NGRAPH, 512, 0, stream>>>(xbuf, score, maskf, gate, alive, hg, Ks[l]);
    }
    k_mlp<<<NGRAPH, 256, 0, stream>>>(inp_c, hg, We, Wa, ba, Wb, bb, Wc, out);
}